// Round 2
// baseline (181.741 us; speedup 1.0000x reference)
//
#include <hip/hip_runtime.h>

typedef float f32x2 __attribute__((ext_vector_type(2)));
typedef float f32x4 __attribute__((ext_vector_type(4)));

#define NLEN   8388608
#define KTAPS  257
#define MPAD   256
#define OUTLEN (NLEN + MPAD)
#define TPB    256
#define RPT    8
#define TILE   (TPB * RPT)          /* 2048 outputs per block */
#define WQ     1160                 /* float4 slots in LDS x window (>= 1156, mult of 8) */
#define NBLK   ((OUTLEN + TILE - 1) / TILE)   /* 4097 */

__device__ __forceinline__ int swz(int q) { return q ^ ((q >> 3) & 7); }

/* packed 2xFP32 FMA: d = a*b + d  (VOP3P, one issue slot for 2 FMAs/lane) */
__device__ __forceinline__ void pk_fma(f32x2& d, f32x2 a, f32x2 b) {
    asm("v_pk_fma_f32 %0, %1, %2, %0" : "+v"(d) : "v"(a), "v"(b));
}

__global__ __launch_bounds__(TPB) void cconv_pk(
    const float* __restrict__ xr, const float* __restrict__ xi,
    const float* __restrict__ wr, const float* __restrict__ wi,
    float* __restrict__ out)
{
    __shared__ f32x4 lxy[WQ];       /* (xr,xi,xr,xi) pairs, swizzled at f4 granularity */
    __shared__ f32x2 pwr[264];      /* (w_r[k], w_r[k]) duplicated pairs */
    __shared__ f32x2 pwi[264];

    const int tid   = threadIdx.x;
    const int tile0 = blockIdx.x * TILE;
    const int b0    = tile0 - MPAD;          /* x index at window position p=0 */

    /* ---- stage weights (duplicated pairs, zero-padded to 264) ---- */
    for (int k = tid; k < 264; k += TPB) {
        float a = (k < KTAPS) ? wr[k] : 0.0f;
        float b = (k < KTAPS) ? wi[k] : 0.0f;
        f32x2 va; va[0] = a; va[1] = a;
        f32x2 vb; vb[0] = b; vb[1] = b;
        pwr[k] = va; pwi[k] = vb;
    }

    /* ---- stage x interleaved, swizzled ---- */
    const bool interior = (b0 >= 0) && (b0 + 2 * WQ <= NLEN);
    if (interior) {
        for (int q = tid; q < WQ; q += TPB) {
            const int g = b0 + 2 * q;
            f32x2 ar = *(const f32x2*)(xr + g);
            f32x2 ai = *(const f32x2*)(xi + g);
            f32x4 v; v[0] = ar[0]; v[1] = ai[0]; v[2] = ar[1]; v[3] = ai[1];
            lxy[swz(q)] = v;
        }
    } else {
        for (int q = tid; q < WQ; q += TPB) {
            const int g = b0 + 2 * q;
            float a0 = 0.f, i0 = 0.f, a1 = 0.f, i1 = 0.f;
            if (g >= 0 && g < NLEN)         { a0 = xr[g];     i0 = xi[g];     }
            if (g + 1 >= 0 && g + 1 < NLEN) { a1 = xr[g + 1]; i1 = xi[g + 1]; }
            f32x4 v; v[0] = a0; v[1] = i0; v[2] = a1; v[3] = i1;
            lxy[swz(q)] = v;
        }
    }
    __syncthreads();

    const f32x2* l2 = (const f32x2*)lxy;     /* f32x2 view: idx = swz(q)*2 + half */

    /* ---- accumulators: P = sum x*(wr,wr), Q = sum x*(wi,wi), x = (xr,xi) ---- */
    f32x2 P[RPT], Q[RPT];
    #pragma unroll
    for (int j = 0; j < RPT; ++j) {
        f32x2 zz; zz[0] = 0.f; zz[1] = 0.f;
        P[j] = zz; Q[j] = zz;
    }

    /* register sliding window: 16 f32x2 slots, slot = (p - tid*8) & 15 */
    f32x2 S2[16];
    const int qb = tid * 4;                  /* float4 index of window p = 8*tid */
    #pragma unroll
    for (int u = 0; u < 16; ++u)
        S2[u] = l2[swz(qb + (u >> 1)) * 2 + (u & 1)];

#define SUBSTEP(D, PAR)                                                          \
    {                                                                            \
        const f32x2 wva = pwr[kb + (D)];                                         \
        const f32x2 wvb = pwi[kb + (D)];                                         \
        _Pragma("unroll")                                                        \
        for (int j = 0; j < RPT; ++j) {                                          \
            const f32x2 x2 = S2[((D) + j + (PAR) * 8) & 15];                     \
            pk_fma(P[j], x2, wva);                                               \
            pk_fma(Q[j], x2, wvb);                                               \
        }                                                                        \
    }

#define PHASE(PAR)                                                               \
    {                                                                            \
        SUBSTEP(0, PAR) SUBSTEP(1, PAR) SUBSTEP(2, PAR) SUBSTEP(3, PAR)          \
        SUBSTEP(4, PAR) SUBSTEP(5, PAR) SUBSTEP(6, PAR) SUBSTEP(7, PAR)          \
        const int qn = qb + (kb >> 1) + 8;                                       \
        _Pragma("unroll")                                                        \
        for (int u = 0; u < 8; ++u)                                              \
            S2[(PAR) * 8 + u] = l2[swz(qn + (u >> 1)) * 2 + (u & 1)];            \
        kb += 8;                                                                 \
    }

    int kb = 0;
    for (int ii = 0; ii < 16; ++ii) {       /* 32 phases: k = 0..255 */
        PHASE(0)
        PHASE(1)
    }

    /* tail tap k = 256: after 32 phases kb=256 ≡ 0 (mod 16) → slot = j */
    {
        const f32x2 wva = pwr[256];
        const f32x2 wvb = pwi[256];
        #pragma unroll
        for (int j = 0; j < RPT; ++j) {
            const f32x2 x2 = S2[j];
            pk_fma(P[j], x2, wva);
            pk_fma(Q[j], x2, wvb);
        }
    }

    /* ---- epilogue: y_r = P.x - Q.y ; y_i = P.y + Q.x ---- */
    const int m0 = tile0 + tid * RPT;
    float y[RPT], z[RPT];
    #pragma unroll
    for (int j = 0; j < RPT; ++j) {
        y[j] = P[j][0] - Q[j][1];
        z[j] = P[j][1] + Q[j][0];
    }
    if (m0 + RPT <= OUTLEN) {
        f32x4 a; a[0] = y[0]; a[1] = y[1]; a[2] = y[2]; a[3] = y[3];
        f32x4 b; b[0] = y[4]; b[1] = y[5]; b[2] = y[6]; b[3] = y[7];
        f32x4 c; c[0] = z[0]; c[1] = z[1]; c[2] = z[2]; c[3] = z[3];
        f32x4 d; d[0] = z[4]; d[1] = z[5]; d[2] = z[6]; d[3] = z[7];
        *(f32x4*)(out + m0)              = a;
        *(f32x4*)(out + m0 + 4)          = b;
        *(f32x4*)(out + OUTLEN + m0)     = c;
        *(f32x4*)(out + OUTLEN + m0 + 4) = d;
    } else {
        for (int j = 0; j < RPT; ++j) {
            if (m0 + j < OUTLEN) {
                out[m0 + j]          = y[j];
                out[OUTLEN + m0 + j] = z[j];
            }
        }
    }
}

extern "C" void kernel_launch(void* const* d_in, const int* in_sizes, int n_in,
                              void* d_out, int out_size, void* d_ws, size_t ws_size,
                              hipStream_t stream) {
    const float* xr = (const float*)d_in[0];
    const float* xi = (const float*)d_in[1];
    const float* wr = (const float*)d_in[2];
    const float* wi = (const float*)d_in[3];
    float* o = (float*)d_out;
    cconv_pk<<<NBLK, TPB, 0, stream>>>(xr, xi, wr, wi, o);
}

// Round 3
// 41.301 us; speedup vs baseline: 4.4004x; 4.4004x over previous
//
#include <hip/hip_runtime.h>

typedef _Float16 half8 __attribute__((ext_vector_type(8)));
typedef float    f32x4 __attribute__((ext_vector_type(4)));

#define NLEN   8388608
#define KTAPS  257
#define MPAD   256
#define OUTLEN (NLEN + MPAD)        /* 8388864 = 256*32769 */
#define TPB    256
#define BT     4096                 /* complex outputs per block */
#define NBLK   ((OUTLEN + BT - 1) / BT)   /* 2049 */
#define NCH    9                    /* K chunks of 32 -> GEMM-K = 288 */
#define XELEM  (BT + 288)           /* staged elems per component: 4384 */
#define XSLOT  (XELEM / 8)          /* 548 16B slots */
#define XPAD   556                  /* + swizzle margin */

__device__ __forceinline__ int swz(int t) { return t ^ ((t >> 3) & 7); }

__global__ __launch_bounds__(TPB, 4) void cconv_mfma(
    const float* __restrict__ xr, const float* __restrict__ xi,
    const float* __restrict__ wr, const float* __restrict__ wi,
    float* __restrict__ out)
{
    __shared__ half8 lx[2][XPAD];        /* staged signal, fp16, swizzled slots */
    __shared__ half8 af[2][NCH][64];     /* weight A-fragments, MFMA layout    */

    const int tid   = threadIdx.x;
    const int wv    = tid >> 6;
    const int lane  = tid & 63;
    const int n15   = lane & 15;
    const int lg    = lane >> 4;
    const int t0    = blockIdx.x * BT;
    const int xbase = t0 - MPAD;         /* global elem of lx slot 0 */

    /* ---- build weight fragments: A[m][j] = w[j-m], lane l: m=l&15, j=32c+8*(l>>4)+e ---- */
    for (int idx = tid; idx < 2 * NCH * 64; idx += TPB) {
        const int comp = idx / (NCH * 64);
        const int rem  = idx % (NCH * 64);
        const int c    = rem >> 6;
        const int l    = rem & 63;
        const int row  = l & 15;
        const int jb   = 32 * c + 8 * (l >> 4);
        const float* wp = comp ? wi : wr;
        half8 v;
        #pragma unroll
        for (int e = 0; e < 8; ++e) {
            const int k = jb + e - row;
            const float f = (k >= 0 && k < KTAPS) ? wp[k] : 0.0f;
            v[e] = (_Float16)f;
        }
        af[comp][c][l] = v;
    }

    /* ---- stage x: fp32 -> fp16, 8 elems per thread per iter, swizzled write ---- */
    #pragma unroll
    for (int it = 0; it < 3; ++it) {
        const int T = it * TPB + tid;
        if (T < XSLOT) {
            const int g = xbase + 8 * T;
            half8 vr, vi;
            if (g >= 0 && g + 8 <= NLEN) {
                const f32x4 a0 = *(const f32x4*)(xr + g);
                const f32x4 a1 = *(const f32x4*)(xr + g + 4);
                const f32x4 b0 = *(const f32x4*)(xi + g);
                const f32x4 b1 = *(const f32x4*)(xi + g + 4);
                #pragma unroll
                for (int e = 0; e < 4; ++e) {
                    vr[e]     = (_Float16)a0[e];
                    vr[e + 4] = (_Float16)a1[e];
                    vi[e]     = (_Float16)b0[e];
                    vi[e + 4] = (_Float16)b1[e];
                }
            } else {
                #pragma unroll
                for (int e = 0; e < 8; ++e) {
                    const int ge = g + e;
                    const bool ok = (ge >= 0) && (ge < NLEN);
                    vr[e] = (_Float16)(ok ? xr[ge] : 0.0f);
                    vi[e] = (_Float16)(ok ? xi[ge] : 0.0f);
                }
            }
            const int Ts = swz(T);
            lx[0][Ts] = vr;
            lx[1][Ts] = vi;
        }
    }
    __syncthreads();

    /* ---- main loop: 4 tiles/wave, 9 K-chunks, 4 MFMAs each ---- */
    f32x4 accr[4], acci[4];
    #pragma unroll
    for (int t = 0; t < 4; ++t) {
        accr[t] = (f32x4)0.0f;
        acci[t] = (f32x4)0.0f;
    }

    const int sT0 = 128 * wv + 2 * n15 + lg;   /* base 16B slot for this lane */

    #pragma unroll
    for (int c = 0; c < NCH; ++c) {
        const half8 awr = af[0][c][lane];
        const half8 awi = af[1][c][lane];
        #pragma unroll
        for (int t = 0; t < 4; ++t) {
            const int T = sT0 + 32 * t + 4 * c;
            const int Ts = swz(T);
            const half8 br  = lx[0][Ts];
            const half8 bi  = lx[1][Ts];
            const half8 bin = -bi;           /* exact fp16 sign flip */
            accr[t] = __builtin_amdgcn_mfma_f32_16x16x32_f16(awr, br,  accr[t], 0, 0, 0);
            accr[t] = __builtin_amdgcn_mfma_f32_16x16x32_f16(awi, bin, accr[t], 0, 0, 0);
            acci[t] = __builtin_amdgcn_mfma_f32_16x16x32_f16(awr, bi,  acci[t], 0, 0, 0);
            acci[t] = __builtin_amdgcn_mfma_f32_16x16x32_f16(awi, br,  acci[t], 0, 0, 0);
        }
    }

    /* ---- epilogue: lane l holds D[4*lg + r][n15], r=0..3 -> 4 consecutive outputs ---- */
    const int obase = t0 + 1024 * wv + 16 * n15 + 4 * lg;
    #pragma unroll
    for (int t = 0; t < 4; ++t) {
        const int tbase = t0 + 1024 * wv + 256 * t;   /* tile base, mult of 256 */
        if (tbase < OUTLEN) {                          /* tiles fully in or out  */
            const int pos = obase + 256 * t;
            *(f32x4*)(out + pos)          = accr[t];
            *(f32x4*)(out + OUTLEN + pos) = acci[t];
        }
    }
}

extern "C" void kernel_launch(void* const* d_in, const int* in_sizes, int n_in,
                              void* d_out, int out_size, void* d_ws, size_t ws_size,
                              hipStream_t stream) {
    const float* xr = (const float*)d_in[0];
    const float* xi = (const float*)d_in[1];
    const float* wr = (const float*)d_in[2];
    const float* wi = (const float*)d_in[3];
    float* o = (float*)d_out;
    cconv_mfma<<<NBLK, TPB, 0, stream>>>(xr, xi, wr, wi, o);
}